// Round 2
// baseline (149.518 us; speedup 1.0000x reference)
//
#include <hip/hip_runtime.h>

// GWD loss: pred(N,5) f32, target(N,5) f32, weight(N) f32 -> scalar mean.
// Round 8: R7's cooperative launch killed the container (coop launch is NOT
// graph-capture-safe in this harness: grid.sync() deadlocks when the graph
// replays it as a plain node). Same fusion goal, capture-safe mechanism:
// last-block-done ticket. Each block agent-scope-stores its partial to ws[],
// tid0 does an agent-scope fetch_add(ACQ_REL) on a 4-byte ticket (ws+NBLK,
// zeroed per-call by a tiny hipMemsetAsync node); the last block reduces
// ws[0..NBLK) + the n%4 tail and writes out[0]. Removes the serialized
// 1-block second kernel (+launch). Fallback: proven R6 two-kernel path.
// Timed region is dominated by two harness-side 256 MiB poison fills
// (~84 us at fill-rate roofline) we cannot control; compute kernel itself
// is at the ~14-15 us HBM read floor (88 MB @ 6.3 TB/s).
// Fast transcendentals: v_sqrt/v_rcp/v_rsq/v_log raw (threshold 4.7e-3).
// FUN='log', TAU=1.0, ALPHA=1.0, LOSS_WEIGHT=1.0.

#define NBLK 1024

__device__ __forceinline__ float gwd_row(const float* __restrict__ p,
                                         const float* __restrict__ t)
{
    const float px = p[0], py = p[1], pw = p[2], ph = p[3], pr = p[4];
    const float tx = t[0], ty = t[1], tw = t[2], th = t[3], tr = t[4];

    const float dx = px - tx;
    const float dy = py - ty;
    const float xy_dist = dx * dx + dy * dy;

    const float a2p = 0.25f * pw * pw;
    const float b2p = 0.25f * ph * ph;
    const float a2t = 0.25f * tw * tw;
    const float b2t = 0.25f * th * th;

    float whr = (a2p + b2p) + (a2t + b2t);

    float cp, sp, ct, st;
    __sincosf(pr, &sp, &cp);
    __sincosf(tr, &st, &ct);

    // Sigma = R diag(a2,b2) R^T
    const float Sp00 = cp * cp * a2p + sp * sp * b2p;
    const float Sp01 = cp * sp * (a2p - b2p);
    const float Sp11 = sp * sp * a2p + cp * cp * b2p;
    const float St00 = ct * ct * a2t + st * st * b2t;
    const float St01 = ct * st * (a2t - b2t);
    const float St11 = st * st * a2t + ct * ct * b2t;

    // tr(Sp^1/2 St Sp^1/2) = tr(Sp St); det(cross) = det(Sp)det(St) >= 0
    const float tr_cross  = Sp00 * St00 + 2.0f * Sp01 * St01 + Sp11 * St11;
    const float det_cross = (a2p * b2p) * (a2t * b2t);

    const float sq = fmaxf(tr_cross + 2.0f * __builtin_amdgcn_sqrtf(det_cross), 0.0f);
    whr = whr - 2.0f * __builtin_amdgcn_sqrtf(sq);

    float d = __builtin_amdgcn_sqrtf(fmaxf(xy_dist + whr, 0.0f));   // ALPHA = 1

    // d /= prod^(1/4)  ==  d *= rsq(sqrt(prod))
    const float prod = (pw * tw) * (ph * th);
    d *= __builtin_amdgcn_rsqf(__builtin_amdgcn_sqrtf(prod));

    // FUN='log': log1p(d) = ln(1+d) = log2(1+d) * ln2  (d >= 0, no cancellation)
    d = 0.69314718056f * __builtin_amdgcn_logf(1.0f + d);

    // TAU=1: 1 - 1/(1+d)
    return 1.0f - __builtin_amdgcn_rcpf(1.0f + d);
}

// Grid-stride over groups of 4 rows, float4-AoS loads (proven fastest R1-R6).
__device__ __forceinline__ float gwd_accum(const float* __restrict__ pred,
                                           const float* __restrict__ target,
                                           const float* __restrict__ weight,
                                           int n)
{
    const int tid = threadIdx.x;
    const int ngroups = n >> 2;                 // full groups of 4 rows
    float acc = 0.0f;

    for (int g = blockIdx.x * 256 + tid; g < ngroups; g += NBLK * 256) {
        const float4* p4 = (const float4*)pred   + (size_t)g * 5;
        const float4* t4 = (const float4*)target + (size_t)g * 5;

        float4 P[5], T[5];
        #pragma unroll
        for (int j = 0; j < 5; ++j) P[j] = p4[j];
        #pragma unroll
        for (int j = 0; j < 5; ++j) T[j] = t4[j];
        const float4 w4 = ((const float4*)weight)[g];

        float pbuf[20], tbuf[20];
        #pragma unroll
        for (int j = 0; j < 5; ++j) { *(float4*)(pbuf + 4 * j) = P[j];
                                      *(float4*)(tbuf + 4 * j) = T[j]; }
        const float w[4] = { w4.x, w4.y, w4.z, w4.w };
        #pragma unroll
        for (int j = 0; j < 4; ++j)
            acc += gwd_row(&pbuf[j * 5], &tbuf[j * 5]) * w[j];
    }
    return acc;
}

// -------- fused kernel: last-block-done ticket (graph-capture-safe) --------

__global__ __launch_bounds__(256) void gwd_fused(
    const float* __restrict__ pred,
    const float* __restrict__ target,
    const float* __restrict__ weight,
    float* __restrict__ ws,
    unsigned int* __restrict__ ticket,   // zeroed per-call by hipMemsetAsync
    float* __restrict__ out,
    int n)
{
    const int tid  = threadIdx.x;
    const int lane = tid & 63;
    const int wid  = tid >> 6;
    __shared__ float wave_sums[4];
    __shared__ bool am_last;

    float acc = gwd_accum(pred, target, weight, n);

    // wave-64 -> block reduction
    #pragma unroll
    for (int off = 32; off > 0; off >>= 1)
        acc += __shfl_down(acc, off, 64);

    if (lane == 0) wave_sums[wid] = acc;
    __syncthreads();

    if (tid == 0) {
        const float s = (wave_sums[0] + wave_sums[1]) + (wave_sums[2] + wave_sums[3]);
        // agent-scope store: visible at the coherent point across XCDs
        __hip_atomic_store(&ws[blockIdx.x], s, __ATOMIC_RELAXED,
                           __HIP_MEMORY_SCOPE_AGENT);
        // ACQ_REL RMW: releases our store, acquires all earlier blocks' stores
        const unsigned int old = __hip_atomic_fetch_add(
            ticket, 1u, __ATOMIC_ACQ_REL, __HIP_MEMORY_SCOPE_AGENT);
        am_last = (old == NBLK - 1);
    }
    __syncthreads();        // broadcasts am_last AND tid0's acquired visibility

    if (!am_last) return;

    // ---- last block: reduce the 1024 partials + n%4 tail, write scalar ----
    float a2 = 0.0f;
    #pragma unroll
    for (int j = 0; j < NBLK / 256; ++j)
        a2 += __hip_atomic_load(&ws[j * 256 + tid], __ATOMIC_RELAXED,
                                __HIP_MEMORY_SCOPE_AGENT);

    const int tail0 = n & ~3;
    if (tid < (n - tail0)) {
        const int r = tail0 + tid;
        float pb[5], tb[5];
        #pragma unroll
        for (int k = 0; k < 5; ++k) {
            pb[k] = pred  [(size_t)r * 5 + k];
            tb[k] = target[(size_t)r * 5 + k];
        }
        a2 += gwd_row(pb, tb) * weight[r];
    }

    #pragma unroll
    for (int off = 32; off > 0; off >>= 1)
        a2 += __shfl_down(a2, off, 64);

    if (lane == 0) wave_sums[wid] = a2;   // safe: all waves past first barrier
    __syncthreads();
    if (tid == 0) {
        const float s = (wave_sums[0] + wave_sums[1]) + (wave_sums[2] + wave_sums[3]);
        out[0] = s * (1.0f / (float)n);   // LOSS_WEIGHT = 1; overwrites poison
    }
}

// ---------------- fallback two-kernel path (identical to R6) ----------------

__global__ __launch_bounds__(256) void gwd_partial(
    const float* __restrict__ pred,
    const float* __restrict__ target,
    const float* __restrict__ weight,
    float* __restrict__ ws,
    int n)
{
    const int tid = threadIdx.x;
    float acc = gwd_accum(pred, target, weight, n);

    #pragma unroll
    for (int off = 32; off > 0; off >>= 1)
        acc += __shfl_down(acc, off, 64);

    __shared__ float wave_sums[4];
    const int lane = tid & 63;
    const int wid  = tid >> 6;
    if (lane == 0) wave_sums[wid] = acc;
    __syncthreads();

    if (tid == 0)
        ws[blockIdx.x] = (wave_sums[0] + wave_sums[1]) + (wave_sums[2] + wave_sums[3]);
}

__global__ __launch_bounds__(256) void gwd_final(
    const float* __restrict__ ws,
    const float* __restrict__ pred,
    const float* __restrict__ target,
    const float* __restrict__ weight,
    float* __restrict__ out,
    int n)
{
    const int tid = threadIdx.x;
    float acc = 0.0f;

    #pragma unroll
    for (int j = 0; j < NBLK / 256; ++j)
        acc += ws[j * 256 + tid];

    const int tail0 = n & ~3;
    if (tid < (n - tail0)) {
        const int r = tail0 + tid;
        float pb[5], tb[5];
        #pragma unroll
        for (int k = 0; k < 5; ++k) {
            pb[k] = pred  [(size_t)r * 5 + k];
            tb[k] = target[(size_t)r * 5 + k];
        }
        acc += gwd_row(pb, tb) * weight[r];
    }

    #pragma unroll
    for (int off = 32; off > 0; off >>= 1)
        acc += __shfl_down(acc, off, 64);

    __shared__ float wave_sums[4];
    const int lane = tid & 63;
    const int wid  = tid >> 6;
    if (lane == 0) wave_sums[wid] = acc;
    __syncthreads();

    if (tid == 0) {
        const float s = (wave_sums[0] + wave_sums[1]) + (wave_sums[2] + wave_sums[3]);
        out[0] = s * (1.0f / (float)n);
    }
}

extern "C" void kernel_launch(void* const* d_in, const int* in_sizes, int n_in,
                              void* d_out, int out_size, void* d_ws, size_t ws_size,
                              hipStream_t stream) {
    const float* pred   = (const float*)d_in[0];
    const float* target = (const float*)d_in[1];
    const float* weight = (const float*)d_in[2];
    float* out = (float*)d_out;
    float* ws  = (float*)d_ws;                       // NBLK partials
    unsigned int* ticket = (unsigned int*)(ws + NBLK);  // 4-byte ticket after them

    const int n = in_sizes[2];   // weight has N elements

    // Tiny capture-safe memset node: zero the ticket (ws is poisoned per call).
    hipError_t e = hipMemsetAsync(ticket, 0, sizeof(unsigned int), stream);
    if (e == hipSuccess) {
        gwd_fused<<<NBLK, 256, 0, stream>>>(pred, target, weight, ws, ticket,
                                            out, n);
    } else {
        (void)hipGetLastError();   // clear sticky error, take proven 2-kernel path
        gwd_partial<<<NBLK, 256, 0, stream>>>(pred, target, weight, ws, n);
        gwd_final<<<1, 256, 0, stream>>>(ws, pred, target, weight, out, n);
    }
}

// Round 3
// 107.425 us; speedup vs baseline: 1.3918x; 1.3918x over previous
//
#include <hip/hip_runtime.h>

// GWD loss: pred(N,5) f32, target(N,5) f32, weight(N) f32 -> scalar mean.
// Round 9: REVERT to the harness-verified R6 two-kernel structure (106.5 us).
// R7 (cooperative fusion) killed the container: coop launch + grid.sync() is
// not graph-capture-safe in this harness. R8 (last-block ticket fusion)
// regressed 107 -> 149.5 us: the 1024-block same-address agent-scope
// ACQ_REL fetch_add chain serializes at ~45-50 ns/RMW at the cross-XCD
// coherence point (= ~50 us), proven by 67.7 us fused-kernel replays with
// only 65 KB of HBM traffic (fully L3-resident -> pure latency, not BW).
// Lesson: on 8-XCD MI355X, cross-XCD ticket barriers cost 10x more than the
// ~5 us second-launch they remove. Two-kernel is the optimal structure.
// Timed-region budget: ~84 us harness 256 MiB poison fills (fill-rate
// roofline, outside .cpp control) + ~14 us mandatory 88 MB read @6.3 TB/s
// + ~5 us launch/final overhead = ~104-107 us floor. We are at it.
// Structure: 1024 blocks, no LDS staging, float4-AoS loads (4 rows/thread/
// group, ~2 groups/thread grid-stride), per-block partials to d_ws (plain
// stores, no atomics), tiny kernel2 reduces + writes out.
// Fast transcendentals: v_sqrt/v_rcp/v_rsq/v_log raw (threshold 4.7e-3).
// FUN='log', TAU=1.0, ALPHA=1.0, LOSS_WEIGHT=1.0.

#define NBLK 1024

__device__ __forceinline__ float gwd_row(const float* __restrict__ p,
                                         const float* __restrict__ t)
{
    const float px = p[0], py = p[1], pw = p[2], ph = p[3], pr = p[4];
    const float tx = t[0], ty = t[1], tw = t[2], th = t[3], tr = t[4];

    const float dx = px - tx;
    const float dy = py - ty;
    const float xy_dist = dx * dx + dy * dy;

    const float a2p = 0.25f * pw * pw;
    const float b2p = 0.25f * ph * ph;
    const float a2t = 0.25f * tw * tw;
    const float b2t = 0.25f * th * th;

    float whr = (a2p + b2p) + (a2t + b2t);

    float cp, sp, ct, st;
    __sincosf(pr, &sp, &cp);
    __sincosf(tr, &st, &ct);

    // Sigma = R diag(a2,b2) R^T
    const float Sp00 = cp * cp * a2p + sp * sp * b2p;
    const float Sp01 = cp * sp * (a2p - b2p);
    const float Sp11 = sp * sp * a2p + cp * cp * b2p;
    const float St00 = ct * ct * a2t + st * st * b2t;
    const float St01 = ct * st * (a2t - b2t);
    const float St11 = st * st * a2t + ct * ct * b2t;

    // tr(Sp^1/2 St Sp^1/2) = tr(Sp St); det(cross) = det(Sp)det(St) >= 0
    const float tr_cross  = Sp00 * St00 + 2.0f * Sp01 * St01 + Sp11 * St11;
    const float det_cross = (a2p * b2p) * (a2t * b2t);

    const float sq = fmaxf(tr_cross + 2.0f * __builtin_amdgcn_sqrtf(det_cross), 0.0f);
    whr = whr - 2.0f * __builtin_amdgcn_sqrtf(sq);

    float d = __builtin_amdgcn_sqrtf(fmaxf(xy_dist + whr, 0.0f));   // ALPHA = 1

    // d /= prod^(1/4)  ==  d *= rsq(sqrt(prod))
    const float prod = (pw * tw) * (ph * th);
    d *= __builtin_amdgcn_rsqf(__builtin_amdgcn_sqrtf(prod));

    // FUN='log': log1p(d) = ln(1+d) = log2(1+d) * ln2  (d >= 0, no cancellation)
    d = 0.69314718056f * __builtin_amdgcn_logf(1.0f + d);

    // TAU=1: 1 - 1/(1+d)
    return 1.0f - __builtin_amdgcn_rcpf(1.0f + d);
}

__global__ __launch_bounds__(256) void gwd_partial(
    const float* __restrict__ pred,
    const float* __restrict__ target,
    const float* __restrict__ weight,
    float* __restrict__ ws,
    int n)
{
    const int tid = threadIdx.x;
    const int ngroups = n >> 2;                 // full groups of 4 rows
    float acc = 0.0f;

    for (int g = blockIdx.x * 256 + tid; g < ngroups; g += NBLK * 256) {
        const float4* p4 = (const float4*)pred   + (size_t)g * 5;
        const float4* t4 = (const float4*)target + (size_t)g * 5;

        float4 P[5], T[5];
        #pragma unroll
        for (int j = 0; j < 5; ++j) P[j] = p4[j];
        #pragma unroll
        for (int j = 0; j < 5; ++j) T[j] = t4[j];
        const float4 w4 = ((const float4*)weight)[g];

        float pbuf[20], tbuf[20];
        #pragma unroll
        for (int j = 0; j < 5; ++j) { *(float4*)(pbuf + 4 * j) = P[j];
                                      *(float4*)(tbuf + 4 * j) = T[j]; }
        const float w[4] = { w4.x, w4.y, w4.z, w4.w };
        #pragma unroll
        for (int j = 0; j < 4; ++j)
            acc += gwd_row(&pbuf[j * 5], &tbuf[j * 5]) * w[j];
    }

    // wave-64 -> block reduction, one plain store per block (no atomics)
    #pragma unroll
    for (int off = 32; off > 0; off >>= 1)
        acc += __shfl_down(acc, off, 64);

    __shared__ float wave_sums[4];
    const int lane = tid & 63;
    const int wid  = tid >> 6;
    if (lane == 0) wave_sums[wid] = acc;
    __syncthreads();

    if (tid == 0)
        ws[blockIdx.x] = (wave_sums[0] + wave_sums[1]) + (wave_sums[2] + wave_sums[3]);
}

__global__ __launch_bounds__(256) void gwd_final(
    const float* __restrict__ ws,
    const float* __restrict__ pred,
    const float* __restrict__ target,
    const float* __restrict__ weight,
    float* __restrict__ out,
    int n)
{
    const int tid = threadIdx.x;
    float acc = 0.0f;

    #pragma unroll
    for (int j = 0; j < NBLK / 256; ++j)
        acc += ws[j * 256 + tid];

    // tail rows (n % 4), handled scalar by the first few threads
    const int tail0 = n & ~3;
    if (tid < (n - tail0)) {
        const int r = tail0 + tid;
        float pb[5], tb[5];
        #pragma unroll
        for (int k = 0; k < 5; ++k) {
            pb[k] = pred  [(size_t)r * 5 + k];
            tb[k] = target[(size_t)r * 5 + k];
        }
        acc += gwd_row(pb, tb) * weight[r];
    }

    #pragma unroll
    for (int off = 32; off > 0; off >>= 1)
        acc += __shfl_down(acc, off, 64);

    __shared__ float wave_sums[4];
    const int lane = tid & 63;
    const int wid  = tid >> 6;
    if (lane == 0) wave_sums[wid] = acc;
    __syncthreads();

    if (tid == 0) {
        const float s = (wave_sums[0] + wave_sums[1]) + (wave_sums[2] + wave_sums[3]);
        out[0] = s * (1.0f / (float)n);   // LOSS_WEIGHT = 1; overwrites poison
    }
}

extern "C" void kernel_launch(void* const* d_in, const int* in_sizes, int n_in,
                              void* d_out, int out_size, void* d_ws, size_t ws_size,
                              hipStream_t stream) {
    const float* pred   = (const float*)d_in[0];
    const float* target = (const float*)d_in[1];
    const float* weight = (const float*)d_in[2];
    float* out = (float*)d_out;
    float* ws  = (float*)d_ws;   // NBLK floats of partials (written every call)

    const int n = in_sizes[2];   // weight has N elements

    gwd_partial<<<NBLK, 256, 0, stream>>>(pred, target, weight, ws, n);
    gwd_final<<<1, 256, 0, stream>>>(ws, pred, target, weight, out, n);
}